// Round 8
// baseline (71.965 us; speedup 1.0000x reference)
//
#include <hip/hip_runtime.h>

#define NB      32
#define NPB     16384
#define KTOP    2048
#define NF      64
#define NBINS   8192        // 13-bit bucket = key32 >> 19
#define CANDCAP 4096
#define NCH     8           // chunks per batch
#define CROWS   2048        // rows per chunk

// Padded LDS index for the bitonic net (u64 elements).
__device__ __forceinline__ int PAD(int i) { return i + (i >> 5); }

// Monotone map: float -> uint32 such that float order == unsigned order.
__device__ __forceinline__ unsigned mono(float f) {
  unsigned u = __float_as_uint(f);
  return (u & 0x80000000u) ? ~u : (u | 0x80000000u);
}

// K1: 256 blocks (one per 2048-row chunk): extract key column + PRIVATE
// per-chunk histogram written with plain stores (no memset, no global atomics).
__global__ __launch_bounds__(256) void extract_hist_kernel(const float* __restrict__ in,
                                                           unsigned* __restrict__ keybuf,
                                                           unsigned* __restrict__ subhist) {
  __shared__ unsigned h[NBINS];                  // 32 KiB
  const int g = blockIdx.x, tid = threadIdx.x;
  for (int i = tid; i < NBINS; i += 256) h[i] = 0;
  __syncthreads();
  const int row0 = g * CROWS;
#pragma unroll
  for (int j = 0; j < CROWS / 256; ++j) {
    int row = row0 + tid + j * 256;
    unsigned k = mono(in[(size_t)row * NF]);
    keybuf[row] = k;
    atomicAdd(&h[k >> 19], 1u);
  }
  __syncthreads();
  uint4* out = (uint4*)(subhist + (size_t)g * NBINS);
  for (int i = tid; i < NBINS / 4; i += 256) out[i] = ((const uint4*)h)[i];
}

// K2: 32 blocks (one per batch): per-bin totals over the 8 sub-hists,
// suffix-scan -> aboveg[] + floor bin D + Ncand; then transform subhist
// IN PLACE into per-(chunk,bin) start offsets (exclusive prefix over chunks).
__global__ __launch_bounds__(512) void scan_kernel(unsigned* __restrict__ subhist,
                                                   unsigned* __restrict__ aboveg,
                                                   uint2* __restrict__ finfo) {
  __shared__ unsigned wtot[8], wsfx[8];
  const int b = blockIdx.x, tid = threadIdx.x;
  const int wid = tid >> 6, lane = tid & 63;

  // Totals for my 16 bins [16*tid, 16*tid+16).
  unsigned tot[16];
#pragma unroll
  for (int j = 0; j < 16; ++j) tot[j] = 0;
  for (int c = 0; c < NCH; ++c) {
    const uint4* hp = (const uint4*)(subhist + (size_t)(b * NCH + c) * NBINS) + 4 * tid;
#pragma unroll
    for (int q = 0; q < 4; ++q) {
      uint4 v = hp[q];
      tot[4*q+0] += v.x; tot[4*q+1] += v.y; tot[4*q+2] += v.z; tot[4*q+3] += v.w;
    }
  }
  unsigned s = 0;
#pragma unroll
  for (int j = 0; j < 16; ++j) s += tot[j];

  unsigned p = s;                                // inclusive suffix over lanes
  for (int off = 1; off < 64; off <<= 1) {
    unsigned t = __shfl_down(p, off);
    if (lane + off < 64) p += t;
  }
  if (lane == 0) wtot[wid] = p;
  __syncthreads();
  if (wid == 0) {
    unsigned own = (lane < 8) ? wtot[lane] : 0;
    unsigned p2 = own;
    for (int off = 1; off < 8; off <<= 1) {
      unsigned t = __shfl_down(p2, off);
      if (lane + off < 8) p2 += t;
    }
    if (lane < 8) wsfx[lane] = p2 - own;         // totals of waves above
  }
  __syncthreads();

  unsigned run = wsfx[wid] + (p - s);            // keys strictly above my bins
  unsigned ab[16];
#pragma unroll
  for (int j = 15; j >= 0; --j) {
    ab[j] = run;                                 // above[bin 16*tid+j]
    run += tot[j];
    if (ab[j] < KTOP && run >= KTOP) {           // exactly one bin satisfies
      unsigned N = run < CANDCAP ? run : CANDCAP;
      finfo[b] = make_uint2((unsigned)(16 * tid + j), N);
    }
  }
  uint4* abo = (uint4*)(aboveg + (size_t)b * NBINS) + 4 * tid;
#pragma unroll
  for (int q = 0; q < 4; ++q)
    abo[q] = make_uint4(ab[4*q], ab[4*q+1], ab[4*q+2], ab[4*q+3]);

  // In-place: subhist[c][bin] -> start offset = above[bin] + sum_{c'<c} subhist[c'][bin].
  unsigned runc[16];
#pragma unroll
  for (int j = 0; j < 16; ++j) runc[j] = ab[j];
  for (int c = 0; c < NCH; ++c) {
    uint4* hp = (uint4*)(subhist + (size_t)(b * NCH + c) * NBINS) + 4 * tid;
#pragma unroll
    for (int q = 0; q < 4; ++q) {
      uint4 v = hp[q];
      hp[q] = make_uint4(runc[4*q], runc[4*q+1], runc[4*q+2], runc[4*q+3]);
      runc[4*q+0] += v.x; runc[4*q+1] += v.y; runc[4*q+2] += v.z; runc[4*q+3] += v.w;
    }
  }
}

// K3: 256 blocks (one per chunk): place winners (bin >= D) at their
// bucket-sorted slot using block-local LDS offset counters only.
__global__ __launch_bounds__(256) void compact_kernel(const unsigned* __restrict__ keybuf,
                                                      const unsigned* __restrict__ ofs_g,
                                                      const uint2* __restrict__ finfo,
                                                      unsigned long long* __restrict__ cand) {
  __shared__ unsigned ofs[NBINS];                // 32 KiB: this chunk's start offsets
  const int g = blockIdx.x, tid = threadIdx.x;
  const int b = g >> 3;
  const unsigned D = finfo[b].x;
  const uint4* src = (const uint4*)(ofs_g + (size_t)g * NBINS);
  for (int i = tid; i < NBINS / 4; i += 256) ((uint4*)ofs)[i] = src[i];
  __syncthreads();

  const int row0 = g * CROWS;
  unsigned long long* cb = cand + (size_t)b * CANDCAP;
#pragma unroll
  for (int j = 0; j < CROWS / 256; ++j) {
    int row = row0 + tid + j * 256;
    unsigned k = keybuf[row];
    unsigned bin = k >> 19;
    if (bin >= D) {
      unsigned slot = atomicAdd(&ofs[bin], 1u);
      if (slot < CANDCAP) {
        unsigned li = (unsigned)(row & (NPB - 1));
        cb[slot] = ((unsigned long long)k << 32) | (unsigned)~li;
      }
    }
  }
}

// K4: 256 blocks (8/batch): sort one bin-aligned chunk [E1,E2) of the
// candidate array in LDS, then gather output rows [E1, min(E2,KTOP)) directly.
__global__ __launch_bounds__(512) void sort_gather_kernel(const float* __restrict__ in,
                                                          const unsigned* __restrict__ aboveg,
                                                          const uint2* __restrict__ finfo,
                                                          const unsigned long long* __restrict__ cand,
                                                          float* __restrict__ out) {
  __shared__ unsigned long long sb[1024 + 32];   // padded bitonic buffer
  __shared__ unsigned shE[2];
  const int g = blockIdx.x, tid = threadIdx.x;
  const int b = g >> 3, cch = g & 7;
  const int lane = tid & 63;

  const unsigned N = finfo[b].y;                 // KTOP <= N <= CANDCAP
  const unsigned x1 = (unsigned)cch * 512u, x2 = x1 + 512u;
  if (x1 >= KTOP) return;                        // chunk entirely past rank KTOP

  if (tid < 2) shE[tid] = 0xffffffffu;
  __syncthreads();
  // E(x) = min{ above[bin] : above[bin] >= x }; N itself is a bin boundary.
  unsigned m1 = 0xffffffffu, m2 = 0xffffffffu;
  const unsigned* ab = aboveg + (size_t)b * NBINS;
  for (int i = tid; i < NBINS; i += 512) {
    unsigned a = ab[i];
    if (a >= x1 && a < m1) m1 = a;
    if (a >= x2 && a < m2) m2 = a;
  }
  for (int off = 1; off < 64; off <<= 1) {
    unsigned t1 = __shfl_xor(m1, off), t2 = __shfl_xor(m2, off);
    m1 = m1 < t1 ? m1 : t1;
    m2 = m2 < t2 ? m2 : t2;
  }
  if (lane == 0) { atomicMin(&shE[0], m1); atomicMin(&shE[1], m2); }
  __syncthreads();

  const unsigned E1 = shE[0];
  unsigned E2 = (x2 >= N) ? N : shE[1];
  if (E2 > N) E2 = N;                            // safety
  if (E1 >= KTOP) return;                        // nothing to output from here
  int len = (int)(E2 - E1);
  if (len <= 0) return;
  if (len > 1024) len = 1024;                    // safety (cannot trigger here)

  const unsigned long long* cb = cand + (size_t)b * CANDCAP;
  for (int e = tid; e < 1024; e += 512)
    sb[PAD(e)] = (e < len) ? cb[E1 + e] : 0ULL;  // 0 sorts below any real key
  __syncthreads();

  for (int size = 2; size <= 1024; size <<= 1) {
    for (int stride = size >> 1; stride >= 1; stride >>= 1) {
      int pos = 2 * tid - (tid & (stride - 1));
      bool desc = ((pos & size) == 0);
      unsigned long long a = sb[PAD(pos)], bb = sb[PAD(pos + stride)];
      if (desc ? (a < bb) : (a > bb)) { sb[PAD(pos)] = bb; sb[PAD(pos + stride)] = a; }
      __syncthreads();
    }
  }

  // Gather output rows [E1, gend).
  const unsigned gend = (E2 < KTOP) ? E2 : KTOP;
  const int glen = (int)(gend - E1);
  const float4* inb = (const float4*)(in + (size_t)b * NPB * NF);
  float4* outb = (float4*)(out + ((size_t)b * KTOP + E1) * NF);
  for (int u = tid; u < glen * 16; u += 512) {
    int r = u >> 4, f4 = u & 15;
    unsigned long long kv = sb[PAD(r)];
    int gi = (int)(~(unsigned)(kv & 0xffffffffu));
    outb[(size_t)r * 16 + f4] = inb[(size_t)gi * 16 + f4];
  }
}

extern "C" void kernel_launch(void* const* d_in, const int* in_sizes, int n_in,
                              void* d_out, int out_size, void* d_ws, size_t ws_size,
                              hipStream_t stream) {
  const float* in = (const float*)d_in[0];
  float* out = (float*)d_out;

  // d_ws layout (MiB offsets): keybuf @0 (2), subhist/ofs @2 (8),
  // aboveg @10 (1), cand @11 (1), finfo @12.
  unsigned* keybuf  = (unsigned*)d_ws;
  unsigned* subhist = (unsigned*)((char*)d_ws + (2u  << 20));
  unsigned* aboveg  = (unsigned*)((char*)d_ws + (10u << 20));
  unsigned long long* cand = (unsigned long long*)((char*)d_ws + (11u << 20));
  uint2* finfo      = (uint2*)((char*)d_ws + (12u << 20));

  extract_hist_kernel<<<NB * NCH, 256, 0, stream>>>(in, keybuf, subhist);
  scan_kernel<<<NB, 512, 0, stream>>>(subhist, aboveg, finfo);
  compact_kernel<<<NB * NCH, 256, 0, stream>>>(keybuf, subhist, finfo, cand);
  sort_gather_kernel<<<NB * NCH, 512, 0, stream>>>(in, aboveg, finfo, cand, out);
}

// Round 9
// 51.283 us; speedup vs baseline: 1.4033x; 1.4033x over previous
//
#include <hip/hip_runtime.h>

#define NB      32
#define NPB     16384
#define KTOP    2048
#define NF      64
#define NBINS   4096        // 12-bit bucket = key32 >> 20
#define CANDCAP 4096
#define NCH     8           // chunks per batch
#define CROWS   2048        // rows per chunk

// Padded LDS index for the bitonic net (u64 elements).
__device__ __forceinline__ int PAD(int i) { return i + (i >> 5); }

// Monotone map: float -> uint32 such that float order == unsigned order.
__device__ __forceinline__ unsigned mono(float f) {
  unsigned u = __float_as_uint(f);
  return (u & 0x80000000u) ? ~u : (u | 0x80000000u);
}

// K1: 256 blocks (one per 2048-row chunk): extract key column + private
// per-chunk histogram, stored as u16 (packed u32 stores, 8 KiB per chunk).
__global__ __launch_bounds__(256) void extract_hist_kernel(const float* __restrict__ in,
                                                           unsigned* __restrict__ keybuf,
                                                           unsigned* __restrict__ subhist32) {
  __shared__ unsigned h[NBINS];                  // 16 KiB
  const int g = blockIdx.x, tid = threadIdx.x;
  for (int i = tid; i < NBINS; i += 256) h[i] = 0;
  __syncthreads();
  const int row0 = g * CROWS;
#pragma unroll
  for (int j = 0; j < CROWS / 256; ++j) {
    int row = row0 + tid + j * 256;
    unsigned k = mono(in[(size_t)row * NF]);
    keybuf[row] = k;
    atomicAdd(&h[k >> 20], 1u);
  }
  __syncthreads();
  unsigned* out = subhist32 + (size_t)g * (NBINS / 2);
  for (int i = tid; i < NBINS / 2; i += 256)
    out[i] = h[2 * i] | (h[2 * i + 1] << 16);    // counts <= 2048, fit u16
}

// K2: 32 blocks (one per batch), 512 threads, 8 bins/thread: batch totals,
// suffix-scan -> aboveg[] + floor bin D + Ncand; rewrite subhist in place
// as per-(chunk,bin) start offsets (u16; all values <= 16384).
__global__ __launch_bounds__(512) void scan_kernel(unsigned short* __restrict__ subhist,
                                                   unsigned* __restrict__ aboveg,
                                                   uint2* __restrict__ finfo) {
  __shared__ unsigned wtot[8], wsfx[8];
  const int b = blockIdx.x, tid = threadIdx.x;
  const int wid = tid >> 6, lane = tid & 63;

  // Per-chunk counts for my 8 bins [8*tid, 8*tid+8).
  unsigned short cnt[NCH][8];
  unsigned tot[8];
#pragma unroll
  for (int j = 0; j < 8; ++j) tot[j] = 0;
  for (int c = 0; c < NCH; ++c) {
    const uint4 v = *(const uint4*)(subhist + (size_t)(b * NCH + c) * NBINS + 8 * tid);
    cnt[c][0] = (unsigned short)(v.x & 0xffff); cnt[c][1] = (unsigned short)(v.x >> 16);
    cnt[c][2] = (unsigned short)(v.y & 0xffff); cnt[c][3] = (unsigned short)(v.y >> 16);
    cnt[c][4] = (unsigned short)(v.z & 0xffff); cnt[c][5] = (unsigned short)(v.z >> 16);
    cnt[c][6] = (unsigned short)(v.w & 0xffff); cnt[c][7] = (unsigned short)(v.w >> 16);
#pragma unroll
    for (int j = 0; j < 8; ++j) tot[j] += cnt[c][j];
  }
  unsigned s = 0;
#pragma unroll
  for (int j = 0; j < 8; ++j) s += tot[j];

  unsigned p = s;                                // inclusive suffix over lanes
  for (int off = 1; off < 64; off <<= 1) {
    unsigned t = __shfl_down(p, off);
    if (lane + off < 64) p += t;
  }
  if (lane == 0) wtot[wid] = p;
  __syncthreads();
  if (wid == 0) {
    unsigned own = (lane < 8) ? wtot[lane] : 0;
    unsigned p2 = own;
    for (int off = 1; off < 8; off <<= 1) {
      unsigned t = __shfl_down(p2, off);
      if (lane + off < 8) p2 += t;
    }
    if (lane < 8) wsfx[lane] = p2 - own;         // totals of waves above
  }
  __syncthreads();

  unsigned run = wsfx[wid] + (p - s);            // keys strictly above my bins
  unsigned ab[8];
#pragma unroll
  for (int j = 7; j >= 0; --j) {
    ab[j] = run;                                 // above[bin 8*tid+j]
    run += tot[j];
    if (ab[j] < KTOP && run >= KTOP) {           // exactly one bin satisfies
      unsigned N = run < CANDCAP ? run : CANDCAP;
      finfo[b] = make_uint2((unsigned)(8 * tid + j), N);
    }
  }
  uint4* abo = (uint4*)(aboveg + (size_t)b * NBINS + 8 * tid);
  abo[0] = make_uint4(ab[0], ab[1], ab[2], ab[3]);
  abo[1] = make_uint4(ab[4], ab[5], ab[6], ab[7]);

  // In place: subhist[c][bin] -> start offset = above[bin] + sum_{c'<c} cnt.
  unsigned runc[8];
#pragma unroll
  for (int j = 0; j < 8; ++j) runc[j] = ab[j];
  for (int c = 0; c < NCH; ++c) {
    uint4 o;
    o.x = (runc[0] & 0xffffu) | (runc[1] << 16);
    o.y = (runc[2] & 0xffffu) | (runc[3] << 16);
    o.z = (runc[4] & 0xffffu) | (runc[5] << 16);
    o.w = (runc[6] & 0xffffu) | (runc[7] << 16);
    *(uint4*)(subhist + (size_t)(b * NCH + c) * NBINS + 8 * tid) = o;
#pragma unroll
    for (int j = 0; j < 8; ++j) runc[j] += cnt[c][j];
  }
}

// K3: 256 blocks (one per chunk): place winners (bin >= D) at their
// bucket-sorted slot using block-local LDS counters seeded from the u16
// offset table (4 KiB read per block).
__global__ __launch_bounds__(256) void compact_kernel(const unsigned* __restrict__ keybuf,
                                                      const unsigned short* __restrict__ ofs16,
                                                      const uint2* __restrict__ finfo,
                                                      unsigned long long* __restrict__ cand) {
  __shared__ unsigned ofs[NBINS];                // 16 KiB
  const int g = blockIdx.x, tid = threadIdx.x;
  const int b = g >> 3;
  const unsigned D = finfo[b].x;
  const uint4* src = (const uint4*)(ofs16 + (size_t)g * NBINS);
  for (int i = tid; i < NBINS / 8; i += 256) {
    uint4 v = src[i];
    ofs[8 * i + 0] = v.x & 0xffffu; ofs[8 * i + 1] = v.x >> 16;
    ofs[8 * i + 2] = v.y & 0xffffu; ofs[8 * i + 3] = v.y >> 16;
    ofs[8 * i + 4] = v.z & 0xffffu; ofs[8 * i + 5] = v.z >> 16;
    ofs[8 * i + 6] = v.w & 0xffffu; ofs[8 * i + 7] = v.w >> 16;
  }
  __syncthreads();

  const int row0 = g * CROWS;
  unsigned long long* cb = cand + (size_t)b * CANDCAP;
#pragma unroll
  for (int j = 0; j < CROWS / 256; ++j) {
    int row = row0 + tid + j * 256;
    unsigned k = keybuf[row];
    unsigned bin = k >> 20;
    if (bin >= D) {
      unsigned slot = atomicAdd(&ofs[bin], 1u);
      if (slot < CANDCAP) {
        unsigned li = (unsigned)(row & (NPB - 1));
        cb[slot] = ((unsigned long long)k << 32) | (unsigned)~li;
      }
    }
  }
}

// K4: 256 blocks (8/batch): sort one bin-aligned chunk [E1,E2) of the
// candidate array in LDS, then gather output rows [E1, min(E2,KTOP)) directly.
__global__ __launch_bounds__(512) void sort_gather_kernel(const float* __restrict__ in,
                                                          const unsigned* __restrict__ aboveg,
                                                          const uint2* __restrict__ finfo,
                                                          const unsigned long long* __restrict__ cand,
                                                          float* __restrict__ out) {
  __shared__ unsigned long long sb[1024 + 32];   // padded bitonic buffer
  __shared__ unsigned shE[2];
  const int g = blockIdx.x, tid = threadIdx.x;
  const int b = g >> 3, cch = g & 7;
  const int lane = tid & 63;

  const unsigned N = finfo[b].y;                 // KTOP <= N <= CANDCAP
  const unsigned x1 = (unsigned)cch * 512u, x2 = x1 + 512u;
  if (x1 >= KTOP) return;                        // chunk entirely past rank KTOP

  if (tid < 2) shE[tid] = 0xffffffffu;
  __syncthreads();
  // E(x) = min{ above[bin] : above[bin] >= x }; N itself is a bin boundary.
  unsigned m1 = 0xffffffffu, m2 = 0xffffffffu;
  const unsigned* ab = aboveg + (size_t)b * NBINS;
  for (int i = tid; i < NBINS; i += 512) {
    unsigned a = ab[i];
    if (a >= x1 && a < m1) m1 = a;
    if (a >= x2 && a < m2) m2 = a;
  }
  for (int off = 1; off < 64; off <<= 1) {
    unsigned t1 = __shfl_xor(m1, off), t2 = __shfl_xor(m2, off);
    m1 = m1 < t1 ? m1 : t1;
    m2 = m2 < t2 ? m2 : t2;
  }
  if (lane == 0) { atomicMin(&shE[0], m1); atomicMin(&shE[1], m2); }
  __syncthreads();

  const unsigned E1 = shE[0];
  unsigned E2 = (x2 >= N) ? N : shE[1];
  if (E2 > N) E2 = N;                            // safety
  if (E1 >= KTOP) return;                        // nothing to output from here
  int len = (int)(E2 - E1);
  if (len <= 0) return;
  if (len > 1024) len = 1024;                    // safety (cannot trigger here)

  const unsigned long long* cb = cand + (size_t)b * CANDCAP;
  for (int e = tid; e < 1024; e += 512)
    sb[PAD(e)] = (e < len) ? cb[E1 + e] : 0ULL;  // 0 sorts below any real key
  __syncthreads();

  for (int size = 2; size <= 1024; size <<= 1) {
    for (int stride = size >> 1; stride >= 1; stride >>= 1) {
      int pos = 2 * tid - (tid & (stride - 1));
      bool desc = ((pos & size) == 0);
      unsigned long long a = sb[PAD(pos)], bb = sb[PAD(pos + stride)];
      if (desc ? (a < bb) : (a > bb)) { sb[PAD(pos)] = bb; sb[PAD(pos + stride)] = a; }
      __syncthreads();
    }
  }

  // Gather output rows [E1, gend).
  const unsigned gend = (E2 < KTOP) ? E2 : KTOP;
  const int glen = (int)(gend - E1);
  const float4* inb = (const float4*)(in + (size_t)b * NPB * NF);
  float4* outb = (float4*)(out + ((size_t)b * KTOP + E1) * NF);
  for (int u = tid; u < glen * 16; u += 512) {
    int r = u >> 4, f4 = u & 15;
    unsigned long long kv = sb[PAD(r)];
    int gi = (int)(~(unsigned)(kv & 0xffffffffu));
    outb[(size_t)r * 16 + f4] = inb[(size_t)gi * 16 + f4];
  }
}

extern "C" void kernel_launch(void* const* d_in, const int* in_sizes, int n_in,
                              void* d_out, int out_size, void* d_ws, size_t ws_size,
                              hipStream_t stream) {
  const float* in = (const float*)d_in[0];
  float* out = (float*)d_out;

  // d_ws layout (MiB offsets): keybuf @0 (2), subhist/ofs u16 @2 (2),
  // aboveg @4 (0.5), cand @5 (1), finfo @6.
  unsigned* keybuf  = (unsigned*)d_ws;
  unsigned* subhist32 = (unsigned*)((char*)d_ws + (2u << 20));
  unsigned short* subhist16 = (unsigned short*)subhist32;
  unsigned* aboveg  = (unsigned*)((char*)d_ws + (4u << 20));
  unsigned long long* cand = (unsigned long long*)((char*)d_ws + (5u << 20));
  uint2* finfo      = (uint2*)((char*)d_ws + (6u << 20));

  extract_hist_kernel<<<NB * NCH, 256, 0, stream>>>(in, keybuf, subhist32);
  scan_kernel<<<NB, 512, 0, stream>>>(subhist16, aboveg, finfo);
  compact_kernel<<<NB * NCH, 256, 0, stream>>>(keybuf, subhist16, finfo, cand);
  sort_gather_kernel<<<NB * NCH, 512, 0, stream>>>(in, aboveg, finfo, cand, out);
}

// Round 10
// 48.271 us; speedup vs baseline: 1.4909x; 1.0624x over previous
//
#include <hip/hip_runtime.h>

#define NB      32
#define NPB     16384
#define KTOP    2048
#define NF      64
#define NBINS   4096        // 12-bit bucket = key32 >> 20
#define CANDCAP 4096
#define NCH     8           // chunks per batch
#define CROWS   2048        // rows per chunk

// Padded LDS index for the bitonic net (u64 elements).
__device__ __forceinline__ int PAD(int i) { return i + (i >> 5); }

// Monotone map: float -> uint32 such that float order == unsigned order.
__device__ __forceinline__ unsigned mono(float f) {
  unsigned u = __float_as_uint(f);
  return (u & 0x80000000u) ? ~u : (u | 0x80000000u);
}

// K1: 256 blocks x 1024 thr (one block per 2048-row chunk): extract key
// column + private per-chunk u16 histogram. 16 waves/CU to hide the
// 256B-strided scattered key loads.
__global__ __launch_bounds__(1024) void extract_hist_kernel(const float* __restrict__ in,
                                                            unsigned* __restrict__ keybuf,
                                                            unsigned* __restrict__ subhist32) {
  __shared__ unsigned h[NBINS];                  // 16 KiB
  const int g = blockIdx.x, tid = threadIdx.x;
  for (int i = tid; i < NBINS; i += 1024) h[i] = 0;
  __syncthreads();
  const int row0 = g * CROWS;
  unsigned k0 = mono(in[(size_t)(row0 + tid) * NF]);
  unsigned k1 = mono(in[(size_t)(row0 + tid + 1024) * NF]);
  keybuf[row0 + tid] = k0;
  keybuf[row0 + tid + 1024] = k1;
  atomicAdd(&h[k0 >> 20], 1u);
  atomicAdd(&h[k1 >> 20], 1u);
  __syncthreads();
  unsigned* out = subhist32 + (size_t)g * (NBINS / 2);
  for (int i = tid; i < NBINS / 2; i += 1024)
    out[i] = h[2 * i] | (h[2 * i + 1] << 16);    // counts <= 2048, fit u16
}

// K23: 256 blocks (one per chunk), 512 threads, 8 bins/thread. Each block
// redundantly computes its batch's suffix-scan from the 8 sub-hists (L2-hot),
// derives floor bin D / Ncand / its own chunk's per-bin start offsets, then
// bucket-places its chunk's winners. cch==0 blocks also write aboveg+finfo.
__global__ __launch_bounds__(512) void scan_compact_kernel(const unsigned* __restrict__ keybuf,
                                                           const unsigned short* __restrict__ subhist,
                                                           unsigned* __restrict__ aboveg,
                                                           uint2* __restrict__ finfo,
                                                           unsigned long long* __restrict__ cand) {
  __shared__ unsigned ofs[NBINS];                // 16 KiB
  __shared__ unsigned wtot[8], wsfx[8];
  __shared__ unsigned sh_D;
  const int g = blockIdx.x, tid = threadIdx.x;
  const int b = g >> 3, cch = g & 7;
  const int wid = tid >> 6, lane = tid & 63;

  // Per-chunk counts for my 8 bins [8*tid, 8*tid+8) across the 8 chunks.
  unsigned short cnt[NCH][8];
  unsigned tot[8];
#pragma unroll
  for (int j = 0; j < 8; ++j) tot[j] = 0;
#pragma unroll
  for (int c = 0; c < NCH; ++c) {
    const uint4 v = *(const uint4*)(subhist + (size_t)(b * NCH + c) * NBINS + 8 * tid);
    cnt[c][0] = (unsigned short)(v.x & 0xffff); cnt[c][1] = (unsigned short)(v.x >> 16);
    cnt[c][2] = (unsigned short)(v.y & 0xffff); cnt[c][3] = (unsigned short)(v.y >> 16);
    cnt[c][4] = (unsigned short)(v.z & 0xffff); cnt[c][5] = (unsigned short)(v.z >> 16);
    cnt[c][6] = (unsigned short)(v.w & 0xffff); cnt[c][7] = (unsigned short)(v.w >> 16);
#pragma unroll
    for (int j = 0; j < 8; ++j) tot[j] += cnt[c][j];
  }
  unsigned s = 0;
#pragma unroll
  for (int j = 0; j < 8; ++j) s += tot[j];

  unsigned p = s;                                // inclusive suffix over lanes
  for (int off = 1; off < 64; off <<= 1) {
    unsigned t = __shfl_down(p, off);
    if (lane + off < 64) p += t;
  }
  if (lane == 0) wtot[wid] = p;
  __syncthreads();
  if (wid == 0) {
    unsigned own = (lane < 8) ? wtot[lane] : 0;
    unsigned p2 = own;
    for (int off = 1; off < 8; off <<= 1) {
      unsigned t = __shfl_down(p2, off);
      if (lane + off < 8) p2 += t;
    }
    if (lane < 8) wsfx[lane] = p2 - own;         // totals of waves above
  }
  __syncthreads();

  unsigned run = wsfx[wid] + (p - s);            // keys strictly above my bins
  unsigned ab[8];
#pragma unroll
  for (int j = 7; j >= 0; --j) {
    ab[j] = run;                                 // above[bin 8*tid+j]
    run += tot[j];
    if (ab[j] < KTOP && run >= KTOP) {           // exactly one bin satisfies
      sh_D = (unsigned)(8 * tid + j);
      if (cch == 0) {
        unsigned N = run < CANDCAP ? run : CANDCAP;
        finfo[b] = make_uint2((unsigned)(8 * tid + j), N);
      }
    }
  }
  if (cch == 0) {
    uint4* abo = (uint4*)(aboveg + (size_t)b * NBINS + 8 * tid);
    abo[0] = make_uint4(ab[0], ab[1], ab[2], ab[3]);
    abo[1] = make_uint4(ab[4], ab[5], ab[6], ab[7]);
  }

  // My chunk's start offsets: above[bin] + sum over earlier chunks' counts.
  unsigned st[8];
#pragma unroll
  for (int j = 0; j < 8; ++j) st[j] = ab[j];
  for (int c = 0; c < NCH; ++c) {
    if (c < cch) {
#pragma unroll
      for (int j = 0; j < 8; ++j) st[j] += cnt[c][j];
    }
  }
#pragma unroll
  for (int j = 0; j < 8; ++j) ofs[8 * tid + j] = st[j];
  __syncthreads();

  // Compact this chunk's winners to their bucket-sorted slots.
  const unsigned D = sh_D;
  const int row0 = g * CROWS;
  unsigned long long* cb = cand + (size_t)b * CANDCAP;
#pragma unroll
  for (int j = 0; j < CROWS / 512; ++j) {
    int row = row0 + tid + j * 512;
    unsigned k = keybuf[row];
    unsigned bin = k >> 20;
    if (bin >= D) {
      unsigned slot = atomicAdd(&ofs[bin], 1u);
      if (slot < CANDCAP) {
        unsigned li = (unsigned)(row & (NPB - 1));
        cb[slot] = ((unsigned long long)k << 32) | (unsigned)~li;
      }
    }
  }
}

// K4: 256 blocks (8/batch): sort one bin-aligned chunk [E1,E2) of the
// candidate array in LDS, then gather output rows [E1, min(E2,KTOP)) directly.
__global__ __launch_bounds__(512) void sort_gather_kernel(const float* __restrict__ in,
                                                          const unsigned* __restrict__ aboveg,
                                                          const uint2* __restrict__ finfo,
                                                          const unsigned long long* __restrict__ cand,
                                                          float* __restrict__ out) {
  __shared__ unsigned long long sb[1024 + 32];   // padded bitonic buffer
  __shared__ unsigned shE[2];
  const int g = blockIdx.x, tid = threadIdx.x;
  const int b = g >> 3, cch = g & 7;
  const int lane = tid & 63;

  const unsigned N = finfo[b].y;                 // KTOP <= N <= CANDCAP
  const unsigned x1 = (unsigned)cch * 512u, x2 = x1 + 512u;
  if (x1 >= KTOP) return;                        // chunk entirely past rank KTOP

  if (tid < 2) shE[tid] = 0xffffffffu;
  __syncthreads();
  // E(x) = min{ above[bin] : above[bin] >= x }; N itself is a bin boundary.
  unsigned m1 = 0xffffffffu, m2 = 0xffffffffu;
  const uint4* ab4 = (const uint4*)(aboveg + (size_t)b * NBINS);
  for (int i = tid; i < NBINS / 4; i += 512) {
    uint4 v = ab4[i];
#pragma unroll
    for (int q = 0; q < 4; ++q) {
      unsigned a = (&v.x)[q];
      if (a >= x1 && a < m1) m1 = a;
      if (a >= x2 && a < m2) m2 = a;
    }
  }
  for (int off = 1; off < 64; off <<= 1) {
    unsigned t1 = __shfl_xor(m1, off), t2 = __shfl_xor(m2, off);
    m1 = m1 < t1 ? m1 : t1;
    m2 = m2 < t2 ? m2 : t2;
  }
  if (lane == 0) { atomicMin(&shE[0], m1); atomicMin(&shE[1], m2); }
  __syncthreads();

  const unsigned E1 = shE[0];
  unsigned E2 = (x2 >= N) ? N : shE[1];
  if (E2 > N) E2 = N;                            // safety
  if (E1 >= KTOP) return;                        // nothing to output from here
  int len = (int)(E2 - E1);
  if (len <= 0) return;
  if (len > 1024) len = 1024;                    // safety (cannot trigger here)

  const unsigned long long* cb = cand + (size_t)b * CANDCAP;
  for (int e = tid; e < 1024; e += 512)
    sb[PAD(e)] = (e < len) ? cb[E1 + e] : 0ULL;  // 0 sorts below any real key
  __syncthreads();

  for (int size = 2; size <= 1024; size <<= 1) {
    for (int stride = size >> 1; stride >= 1; stride >>= 1) {
      int pos = 2 * tid - (tid & (stride - 1));
      bool desc = ((pos & size) == 0);
      unsigned long long a = sb[PAD(pos)], bb = sb[PAD(pos + stride)];
      if (desc ? (a < bb) : (a > bb)) { sb[PAD(pos)] = bb; sb[PAD(pos + stride)] = a; }
      __syncthreads();
    }
  }

  // Gather output rows [E1, gend).
  const unsigned gend = (E2 < KTOP) ? E2 : KTOP;
  const int glen = (int)(gend - E1);
  const float4* inb = (const float4*)(in + (size_t)b * NPB * NF);
  float4* outb = (float4*)(out + ((size_t)b * KTOP + E1) * NF);
  for (int u = tid; u < glen * 16; u += 512) {
    int r = u >> 4, f4 = u & 15;
    unsigned long long kv = sb[PAD(r)];
    int gi = (int)(~(unsigned)(kv & 0xffffffffu));
    outb[(size_t)r * 16 + f4] = inb[(size_t)gi * 16 + f4];
  }
}

extern "C" void kernel_launch(void* const* d_in, const int* in_sizes, int n_in,
                              void* d_out, int out_size, void* d_ws, size_t ws_size,
                              hipStream_t stream) {
  const float* in = (const float*)d_in[0];
  float* out = (float*)d_out;

  // d_ws layout (MiB offsets): keybuf @0 (2), subhist u16 @2 (2),
  // aboveg @4 (0.5), cand @5 (1), finfo @6.
  unsigned* keybuf    = (unsigned*)d_ws;
  unsigned* subhist32 = (unsigned*)((char*)d_ws + (2u << 20));
  unsigned short* subhist16 = (unsigned short*)subhist32;
  unsigned* aboveg    = (unsigned*)((char*)d_ws + (4u << 20));
  unsigned long long* cand = (unsigned long long*)((char*)d_ws + (5u << 20));
  uint2* finfo        = (uint2*)((char*)d_ws + (6u << 20));

  extract_hist_kernel<<<NB * NCH, 1024, 0, stream>>>(in, keybuf, subhist32);
  scan_compact_kernel<<<NB * NCH, 512, 0, stream>>>(keybuf, subhist16, aboveg, finfo, cand);
  sort_gather_kernel<<<NB * NCH, 512, 0, stream>>>(in, aboveg, finfo, cand, out);
}